// Round 4
// baseline (1195.975 us; speedup 1.0000x reference)
//
#include <hip/hip_runtime.h>
#include <hip/hip_bf16.h>

typedef unsigned short u16;
typedef unsigned int   u32;
typedef unsigned long long u64;
typedef __attribute__((ext_vector_type(4)))  float  f32x4;
typedef __attribute__((ext_vector_type(8)))  short  short8;
typedef __attribute__((ext_vector_type(16))) float  f32x16;

#define MB     256
#define SRCT   120
#define DECT   24
#define NSTEP  144
#define DIN    216
#define HDIM   1024
#define KXP    224
#define KA     1248
#define NGATE  4096
#define OUTD   216
#define NWG    256

// ---- ws layout (bytes) ----
#define OFF_SRCBF 0u
#define OFF_H     13762560u
#define OFF_XDEC  14811136u
#define OFF_WCAT  14925824u
#define OFF_WO    25149440u
#define OFF_BAR   25591808u      // 8 groups x 128 u32 (4 striped lines, accumulating)

__device__ __forceinline__ u16 f2bf(float f) {
    union { float f; unsigned v; } c; c.f = f;
    return (u16)((c.v + 0x7FFFu + ((c.v >> 16) & 1u)) >> 16);
}
__device__ __forceinline__ float sigm(float x)  { return 1.0f / (1.0f + __expf(-x)); }
__device__ __forceinline__ float tanh_(float x) { return 1.0f - 2.0f / (1.0f + __expf(2.0f * x)); }

// plain write-back store: lands in the LOCAL XCD L2 (group == XCD).
__device__ __forceinline__ void pstore(u64* p, u64 v) { *p = v; }

// L2-coherent 16B load: sc0 bypasses L1, hits the XCD-local L2. [proven R2]
__device__ __forceinline__ short8 ld_l2(const u16* p) {
    short8 r;
    asm volatile("global_load_dwordx4 %0, %1, off sc0" : "=v"(r) : "v"(p));
    return r;
}
template <int N>
__device__ __forceinline__ void vwait() {
    asm volatile("s_waitcnt vmcnt(%0)" :: "n"(N));
    __builtin_amdgcn_sched_barrier(0);   // keep MFMAs from hoisting above the wait
}

// ---- group barrier: AGENT-scope flags (R2-proven domain), striped slots ----
// Layout per group: 4 stripes x 32 u32 (stripes 128B apart); slot(k,s) =
// (s&3)*32 + (k&7); counters accumulate forever; per-stripe target
// 8*((k>>3)+1). Slot reuse distance is 8 barriers; max WG skew is 1 (each
// arrive at k+1 is ordered after passing poll k), so no wrap hazard.
__device__ __forceinline__ void flag_add(u32* slots, int k, int s) {
    __hip_atomic_fetch_add(slots + (s & 3) * 32 + (k & 7), 1u,
                           __ATOMIC_RELAXED, __HIP_MEMORY_SCOPE_AGENT);
}
__device__ __forceinline__ void g_arrive(u32* gslots, int k, int s) {
    __syncthreads();   // each wave drains vmcnt(0) before s_barrier => stores in L2
    if (threadIdx.x == 0) {
        asm volatile("s_waitcnt vmcnt(0)" ::: "memory");
        flag_add(gslots, k, s);
    }
}
// wave-level wait, no syncthreads release: lanes 0..3 of each wave poll the 4
// stripe counters; exec-mask divergence retires lanes as their stripe passes.
__device__ __forceinline__ void wave_poll(const u32* gslots, int k) {
    const u32 tgt = 8u * (u32)((k >> 3) + 1);
    const int l = threadIdx.x & 63;
    if (l < 4) {
        const u32* a = gslots + l * 32 + (k & 7);
        while (__hip_atomic_load(a, __ATOMIC_RELAXED, __HIP_MEMORY_SCOPE_AGENT) < tgt)
            __builtin_amdgcn_s_sleep(1);
    }
    __builtin_amdgcn_sched_barrier(0);
}

// ---------------- prep: fp32 -> bf16, transposed comm layouts ----------------
__global__ void prep_kernel(const float* __restrict__ src,
                            const float* __restrict__ W_ih,
                            const float* __restrict__ W_hh,
                            const float* __restrict__ W_out,
                            u16* __restrict__ srcbf, u16* __restrict__ H,
                            u16* __restrict__ Xd,    u16* __restrict__ Wcat,
                            u16* __restrict__ Wo,    u32* __restrict__ bar) {
    const int nS  = SRCT * 8 * 28 * 256;
    const int nW  = NGATE * KA;
    const int nWo = OUTD * HDIM;
    const int nH  = MB * HDIM;
    const int nXd = 8 * 28 * 256;
    const int nB  = 8 * 128;
    const int total = nS + nW + nWo + nH + nXd + nB;
    for (int i = blockIdx.x * blockDim.x + threadIdx.x; i < total; i += gridDim.x * blockDim.x) {
        if (i < nS) {
            int r = i & 255, i2 = i >> 8;
            int m = r >> 3, e = r & 7;
            int oct = i2 % 28, q = i2 / 28;
            int gi = q & 7, t = q >> 3;
            int col = oct * 8 + e, b = gi * 32 + m;
            srcbf[i] = (col < DIN) ? f2bf(src[((size_t)b * SRCT + t) * DIN + col]) : (u16)0;
        } else if (i < nS + nW) {
            int j = i - nS;
            int r = j / KA, col = j % KA;
            u16 v = 0;
            if (col < DIN)       v = f2bf(W_ih[(size_t)r * DIN + col]);
            else if (col >= KXP) v = f2bf(W_hh[(size_t)r * HDIM + (col - KXP)]);
            Wcat[j] = v;
        } else if (i < nS + nW + nWo) {
            int j = i - nS - nW;
            Wo[j] = f2bf(W_out[j]);
        } else if (i < nS + nW + nWo + nH) {
            H[i - nS - nW - nWo] = 0;
        } else if (i < nS + nW + nWo + nH + nXd) {
            Xd[i - nS - nW - nWo - nH] = 0;   // also zeroes the 8 claim counters
        } else {
            bar[i - nS - nW - nWo - nH - nXd] = 0;
        }
    }
}

// ---------------- gate GEMM: direct-load A-fragment pipeline ----------------
// Per-wave tile order (h-first): J<16 -> h-tile, addr hbw + J*512; J>=16 ->
// x-tile xbase_p + (J-16), addr xbw + (J-16)*512; pad tiles (J-16>=xcnt)
// reuse the last x addr with zeroed B. The Xd-ready poll (decoder) is
// injected before issuing the first x load (body J==8), covered by 8
// h-tiles of in-flight loads + 32 MFMAs.
template <int J>
__device__ __forceinline__ void gate_issue2(short8 (&av)[20], const u16* hbw,
                                            const u16* xbw, int xcnt) {
    if constexpr (J < 16) {
        av[J] = ld_l2(hbw + J * 512);
    } else {
        int xt = J - 16; if (xt >= xcnt) xt = xcnt - 1;
        av[J] = ld_l2(xbw + xt * 512);
    }
}
template <int J>
__device__ __forceinline__ void gate_pro2(short8 (&av)[20], const u16* hbw,
                                          const u16* xbw, int xcnt) {
    gate_issue2<J>(av, hbw, xbw, xcnt);
    if constexpr (J + 1 < 8) gate_pro2<J + 1>(av, hbw, xbw, xcnt);
}
template <int J>
__device__ __forceinline__ void gate_body2(short8 (&av)[20], short8 (&Bf)[4][20], f32x16 (&acc)[4],
                                           const u16* hbw, const u16* xbw, int xcnt,
                                           const u32* gslots, int pollk) {
    if constexpr (J + 8 < 20) {
        if constexpr (J + 8 == 16) {
            if (pollk >= 0) wave_poll(gslots, pollk);   // Xd-ready, before first x load
        }
        gate_issue2<J + 8>(av, hbw, xbw, xcnt);
    }
    vwait<(J + 8 < 20) ? 8 : (19 - J)>();
    acc[0] = __builtin_amdgcn_mfma_f32_32x32x16_bf16(av[J], Bf[0][J], acc[0], 0, 0, 0);
    acc[1] = __builtin_amdgcn_mfma_f32_32x32x16_bf16(av[J], Bf[1][J], acc[1], 0, 0, 0);
    acc[2] = __builtin_amdgcn_mfma_f32_32x32x16_bf16(av[J], Bf[2][J], acc[2], 0, 0, 0);
    acc[3] = __builtin_amdgcn_mfma_f32_32x32x16_bf16(av[J], Bf[3][J], acc[3], 0, 0, 0);
    if constexpr (J + 1 < 20) gate_body2<J + 1>(av, Bf, acc, hbw, xbw, xcnt, gslots, pollk);
}

// ---------------- out GEMM: direct-load A (h_new), B from Wo ----------------
template <int J>
__device__ __forceinline__ void out_issue(short8 (&av)[16], const u16* hb, int kt0, int lo) {
    const int o2 = 2 * (kt0 + J);
    av[J] = ld_l2(hb + o2 * 256 + lo);
}
template <int J>
__device__ __forceinline__ void out_pro(short8 (&av)[16], const u16* hb, int kt0, int lo) {
    out_issue<J>(av, hb, kt0, lo);
    if constexpr (J + 1 < 8) out_pro<J + 1>(av, hb, kt0, lo);
}
template <int J>
__device__ __forceinline__ void out_body(short8 (&av)[16], f32x16& oacc, const u16* hb,
                                         const u16* wob, int kt0, int lo) {
    if constexpr (J + 8 < 16) out_issue<J + 8>(av, hb, kt0, lo);
    vwait<(J + 8 < 16) ? 8 : (15 - J)>();
    short8 bf = *(const short8*)(wob + (size_t)(kt0 + J) * 16);
    oacc = __builtin_amdgcn_mfma_f32_32x32x16_bf16(av[J], bf, oacc, 0, 0, 0);
    if constexpr (J + 1 < 16) out_body<J + 1>(av, oacc, hb, wob, kt0, lo);
}

// ---------------- persistent LSTM ----------------
// group g = XCD id (HW_REG_XCC_ID), slice s = per-XCD claim (0..31).
// All group DATA traffic intra-XCD (local L2, plain stores + sc0 loads);
// barrier FLAGS on the AGENT/IC path (R2-proven), 4-way striped.
__global__ void __launch_bounds__(256, 1)
lstm_persist(const u16* __restrict__ srcbf, u16* __restrict__ H,
             u16* __restrict__ Xd, const u16* __restrict__ Wcat,
             const u16* __restrict__ Wo,
             const float* __restrict__ b_ih, const float* __restrict__ b_hh,
             const float* __restrict__ b_out,
             float* __restrict__ dout, u32* __restrict__ bar)
{
    __shared__ __align__(16) float G2[16 * 32 * 36];   // [slab][col][b36] 73,728 B
    __shared__ __align__(16) u16  Hx[4 * 32 * 8];      // transpose tile 2 KB
    __shared__ __align__(16) char lds_pad[8192];       // >80KB => 1 WG/CU (claim needs it)
    __shared__ int gs_share[2];

    const int tid  = threadIdx.x;
    const int p    = tid >> 6;
    const int lane = tid & 63;
    const int l31  = lane & 31;
    const int kg   = lane >> 5;
    const int lo   = kg * 256 + l31 * 8;

    if (tid == 255) *(volatile char*)lds_pad = 0;      // keep pad allocated

    // ---- XCD discovery + slice claim (counters in Xd[0..7], zeroed by prep) ----
    if (tid == 0) {
        u32 xcc;
        asm volatile("s_getreg_b32 %0, hwreg(HW_REG_XCC_ID)" : "=s"(xcc));
        u32 myidx = __hip_atomic_fetch_add((u32*)Xd + xcc, 1u,
                                           __ATOMIC_RELAXED, __HIP_MEMORY_SCOPE_AGENT);
        gs_share[0] = (int)xcc;
        gs_share[1] = (int)myidx;
    }
    __syncthreads();
    const int g  = gs_share[0];
    const int s  = gs_share[1];
    const int b0 = g * 32;

    u32* gslots = bar + g * 128;
    u16* Xdg = Xd + (size_t)g * 7168;

    // K-split (h-first order): wave p owns h-tiles kt=14+p*16+{0..15} and
    // x-tiles kt=xbase_p+{0..xcnt_p-1}; xcnt={4,4,3,3}, xbase={0,4,8,11}.
    const int xcnt  = (p < 2) ? 4 : 3;
    const int xbase = p * 4 - (p == 3 ? 1 : 0);

    // ---- pin B for all 4 gates in the per-wave tile order (pads zeroed) ----
    short8 Bfrag[4][20];
#pragma unroll
    for (int gg = 0; gg < 4; ++gg) {
        const u16* pw = Wcat + (size_t)(gg * 1024 + s * 32 + l31) * KA + kg * 8;
#pragma unroll
        for (int j = 0; j < 20; ++j) {
            int kt; bool valid = true;
            if (j < 16) kt = 14 + p * 16 + j;
            else { int xt = j - 16; if (xt < xcnt) kt = xbase + xt; else { kt = 0; valid = false; } }
            Bfrag[gg][j] = valid ? *(const short8*)(pw + (size_t)kt * 16) : short8{};
        }
    }

    // pointwise mapping: thread -> (col cs, 4 batches bq*4..)
    const int cs = tid & 31;
    const int bq = tid >> 5;
    float creg[4] = {0.f, 0.f, 0.f, 0.f};
    const int hcg = s * 32 + cs;
    const float bI  = b_ih[hcg]        + b_hh[hcg];
    const float bF  = b_ih[1024 + hcg] + b_hh[1024 + hcg];
    const float bG_ = b_ih[2048 + hcg] + b_hh[2048 + hcg];
    const float bO  = b_ih[3072 + hcg] + b_hh[3072 + hcg];
    const float bOutv = (s < 7 && hcg < OUTD) ? b_out[hcg] : 0.f;

    for (int t = 0; t < NSTEP; ++t) {
        const u16* hb    = H + (size_t)(t & 1) * (MB * HDIM) + (size_t)g * 32768;  // h_t
        u16*       HTn   = H + (size_t)((t + 1) & 1) * (MB * HDIM);
        const u16* hnext = HTn + (size_t)g * 32768;                                // h_{t+1}
        const u16* xb;
        if (t < SRCT)       xb = srcbf + (size_t)(t * 8 + g) * 7168;
        else if (t == SRCT) xb = srcbf + (size_t)((SRCT - 1) * 8 + g) * 7168;
        else                xb = Xdg;

        // deferred waits: s>=7 decoder WGs certify h here (they skipped the k1
        // wait); everyone certifies Xd inside the pipeline at J==8.
        const int upk   = (t > SRCT && s >= 7) ? (2 * t - SRCT - 2) : -1;  // h-ready
        const int pollk = (t > SRCT)           ? (2 * t - SRCT - 1) : -1;  // Xd-ready
        if (upk >= 0) wave_poll(gslots, upk);

        // ---- gate GEMM: pipelined L2 loads feeding pinned-B MFMAs ----
        f32x16 acc[4] = {f32x16{}, f32x16{}, f32x16{}, f32x16{}};
        {
            short8 av[20];
            const u16* hbw = hb + p * 8192 + lo;
            const u16* xbw = xb + (size_t)xbase * 512 + lo;
            gate_pro2<0>(av, hbw, xbw, xcnt);
            gate_body2<0>(av, Bfrag, acc, hbw, xbw, xcnt, gslots, pollk);
        }
#pragma unroll
        for (int gg = 0; gg < 4; ++gg) {
#pragma unroll
            for (int rq = 0; rq < 4; ++rq) {
                f32x4 v;
                v[0] = acc[gg][rq * 4 + 0]; v[1] = acc[gg][rq * 4 + 1];
                v[2] = acc[gg][rq * 4 + 2]; v[3] = acc[gg][rq * 4 + 3];
                *(f32x4*)&G2[(size_t)((gg * 4 + p) * 32 + l31) * 36 + rq * 8 + kg * 4] = v;
            }
        }
        __syncthreads();

        // ---- pointwise cell ----
        {
            f32x4 sg[4];
#pragma unroll
            for (int gg = 0; gg < 4; ++gg) {
                f32x4 a = *(const f32x4*)&G2[(size_t)((gg * 4 + 0) * 32 + cs) * 36 + bq * 4];
#pragma unroll
                for (int pp = 1; pp < 4; ++pp)
                    a += *(const f32x4*)&G2[(size_t)((gg * 4 + pp) * 32 + cs) * 36 + bq * 4];
                sg[gg] = a;
            }
#pragma unroll
            for (int i = 0; i < 4; ++i) {
                float gi = sg[0][i] + bI, gf = sg[1][i] + bF;
                float gG = sg[2][i] + bG_, go = sg[3][i] + bO;
                float c = sigm(gf) * creg[i] + sigm(gi) * tanh_(gG);
                creg[i] = c;
                Hx[(cs >> 3) * 256 + (bq * 4 + i) * 8 + (cs & 7)] = f2bf(sigm(go) * tanh_(c));
            }
        }
        __syncthreads();
        // coalesced write-through of this WG's h slice into the LOCAL L2
        pstore((u64*)HTn + (size_t)g * 8192 + s * 256 + tid, ((const u64*)Hx)[tid]);

        if (t < SRCT) {
            g_arrive(gslots, t, s);
            wave_poll(gslots, t);           // h_{t+1} ready; next gate runs free
        } else {
            const int d  = t - SRCT;
            const int k1 = SRCT + 2 * d;
            g_arrive(gslots, k1, s);
            if (s < 7) {
                wave_poll(gslots, k1);      // h_{t+1} ready for out-GEMM
                f32x16 oacc = {};
                const int orow = (s * 32 + l31 < OUTD) ? (s * 32 + l31) : (OUTD - 1);
                const u16* wob = Wo + (size_t)orow * HDIM + kg * 8;
                short8 av2[16];
                out_pro<0>(av2, hnext, p * 16, lo);
                out_body<0>(av2, oacc, hnext, wob, p * 16, lo);
#pragma unroll
                for (int rq = 0; rq < 4; ++rq) {
                    f32x4 v;
                    v[0] = oacc[rq * 4 + 0]; v[1] = oacc[rq * 4 + 1];
                    v[2] = oacc[rq * 4 + 2]; v[3] = oacc[rq * 4 + 3];
                    *(f32x4*)&G2[(size_t)(p * 32 + l31) * 36 + rq * 8 + kg * 4] = v;
                }
                __syncthreads();
                {
                    const int  ocol = s * 32 + cs;
                    const bool real = ocol < OUTD;
                    f32x4 S = *(const f32x4*)&G2[(size_t)(0 * 32 + cs) * 36 + bq * 4];
#pragma unroll
                    for (int pp = 1; pp < 4; ++pp)
                        S += *(const f32x4*)&G2[(size_t)(pp * 32 + cs) * 36 + bq * 4];
#pragma unroll
                    for (int i = 0; i < 4; ++i) {
                        float v = real ? (S[i] + bOutv) : 0.f;
                        Hx[(cs >> 3) * 256 + (bq * 4 + i) * 8 + (cs & 7)] = real ? f2bf(v) : (u16)0;
                        if (real)
                            dout[(size_t)(b0 + bq * 4 + i) * (DECT * OUTD) + (size_t)d * OUTD + ocol] = v;
                    }
                }
                __syncthreads();
                pstore((u64*)Xdg + s * 256 + tid, ((const u64*)Hx)[tid]);
                if (t < NSTEP - 1)
                    g_arrive(gslots, k1 + 1, s);   // Xd ready (syncthreads drains stores)
            } else {
                // nothing produced since k1: arrive at k1+1 immediately; the
                // h-ready (k1) wait is deferred to next gate's upfront poll.
                if (t < NSTEP - 1 && tid == 0)
                    flag_add(gslots, k1 + 1, s);
            }
        }
    }
}

extern "C" void kernel_launch(void* const* d_in, const int* in_sizes, int n_in,
                              void* d_out, int out_size, void* d_ws, size_t ws_size,
                              hipStream_t stream) {
    const float* src   = (const float*)d_in[0];
    // d_in[1] = tgt (unused in eval forward)
    const float* W_ih  = (const float*)d_in[2];
    const float* W_hh  = (const float*)d_in[3];
    const float* b_ih  = (const float*)d_in[4];
    const float* b_hh  = (const float*)d_in[5];
    const float* W_out = (const float*)d_in[6];
    const float* b_out = (const float*)d_in[7];
    float* out = (float*)d_out;

    char* ws = (char*)d_ws;
    u16* srcbf = (u16*)(ws + OFF_SRCBF);
    u16* H     = (u16*)(ws + OFF_H);
    u16* Xd    = (u16*)(ws + OFF_XDEC);
    u16* Wcat  = (u16*)(ws + OFF_WCAT);
    u16* Wo    = (u16*)(ws + OFF_WO);
    u32* bar   = (u32*)(ws + OFF_BAR);

    hipLaunchKernelGGL(prep_kernel, dim3(2048), dim3(256), 0, stream,
                       src, W_ih, W_hh, W_out, srcbf, H, Xd, Wcat, Wo, bar);

    hipLaunchKernelGGL(lstm_persist, dim3(NWG), dim3(256), 0, stream,
                       srcbf, H, Xd, Wcat, Wo, b_ih, b_hh, b_out, out, bar);
}

// Round 5
// 972.572 us; speedup vs baseline: 1.2297x; 1.2297x over previous
//
#include <hip/hip_runtime.h>
#include <hip/hip_bf16.h>

typedef unsigned short u16;
typedef unsigned int   u32;
typedef unsigned long long u64;
typedef __attribute__((ext_vector_type(4)))  float  f32x4;
typedef __attribute__((ext_vector_type(8)))  short  short8;
typedef __attribute__((ext_vector_type(16))) float  f32x16;

#define MB     256
#define SRCT   120
#define DECT   24
#define NSTEP  144
#define DIN    216
#define HDIM   1024
#define KXP    224
#define KA     1248
#define NGATE  4096
#define OUTD   216
#define NWG    256

// ---- ws layout (bytes) ----
#define OFF_SRCBF 0u
#define OFF_H     13762560u
#define OFF_XDEC  14811136u
#define OFF_WCAT  14925824u
#define OFF_WO    25149440u
#define OFF_BAR   25591808u      // 8 groups x 128 u32 (4 striped lines, accumulating)

__device__ __forceinline__ u16 f2bf(float f) {
    union { float f; unsigned v; } c; c.f = f;
    return (u16)((c.v + 0x7FFFu + ((c.v >> 16) & 1u)) >> 16);
}
__device__ __forceinline__ float sigm(float x)  { return 1.0f / (1.0f + __expf(-x)); }
__device__ __forceinline__ float tanh_(float x) { return 1.0f - 2.0f / (1.0f + __expf(2.0f * x)); }

// plain write-back store: lands in the LOCAL XCD L2 (group == XCD).
__device__ __forceinline__ void pstore(u64* p, u64 v) { *p = v; }

// L2-coherent 16B load: sc0 bypasses L1, hits the XCD-local L2. [proven R2]
__device__ __forceinline__ short8 ld_l2(const u16* p) {
    short8 r;
    asm volatile("global_load_dwordx4 %0, %1, off sc0" : "=v"(r) : "v"(p));
    return r;
}
template <int N>
__device__ __forceinline__ void vwait() {
    asm volatile("s_waitcnt vmcnt(%0)" :: "n"(N));
    __builtin_amdgcn_sched_barrier(0);   // keep MFMAs from hoisting above the wait
}

// ---- group barrier: AGENT-scope flags, striped arrivals, single poller ----
// Per group: 4 stripes x 32 u32 (stripes 128B apart = distinct lines);
// slot(k,s) = (s&3)*32 + (k&7). Counters accumulate forever; per-stripe
// target 8*((k>>3)+1). Reuse distance 8 barriers >> max WG skew (~3).
// Arrivals: 8 RMWs per line (4x less serialization than one line).
// Wait: tid0 ONLY polls (256 pollers chip-wide, R2-proven pressure),
// __syncthreads release.
__device__ __forceinline__ void flag_add(u32* slots, int k, int s) {
    __hip_atomic_fetch_add(slots + (s & 3) * 32 + (k & 7), 1u,
                           __ATOMIC_RELAXED, __HIP_MEMORY_SCOPE_AGENT);
}
__device__ __forceinline__ void g_arrive(u32* gslots, int k, int s) {
    __syncthreads();   // each wave drains vmcnt(0) before s_barrier => stores visible
    if (threadIdx.x == 0) {
        asm volatile("s_waitcnt vmcnt(0)" ::: "memory");
        flag_add(gslots, k, s);
    }
}
__device__ __forceinline__ void g_wait(u32* gslots, int k) {
    if (threadIdx.x == 0) {
        const u32 tgt = 8u * (u32)((k >> 3) + 1);
        const u32* a = gslots + (k & 7);
        for (;;) {
            u32 v0 = __hip_atomic_load(a,      __ATOMIC_RELAXED, __HIP_MEMORY_SCOPE_AGENT);
            u32 v1 = __hip_atomic_load(a + 32, __ATOMIC_RELAXED, __HIP_MEMORY_SCOPE_AGENT);
            u32 v2 = __hip_atomic_load(a + 64, __ATOMIC_RELAXED, __HIP_MEMORY_SCOPE_AGENT);
            u32 v3 = __hip_atomic_load(a + 96, __ATOMIC_RELAXED, __HIP_MEMORY_SCOPE_AGENT);
            if (v0 >= tgt && v1 >= tgt && v2 >= tgt && v3 >= tgt) break;
            __builtin_amdgcn_s_sleep(1);
        }
    }
    __syncthreads();
}

// ---------------- prep: fp32 -> bf16, transposed comm layouts ----------------
__global__ void prep_kernel(const float* __restrict__ src,
                            const float* __restrict__ W_ih,
                            const float* __restrict__ W_hh,
                            const float* __restrict__ W_out,
                            u16* __restrict__ srcbf, u16* __restrict__ H,
                            u16* __restrict__ Xd,    u16* __restrict__ Wcat,
                            u16* __restrict__ Wo,    u32* __restrict__ bar) {
    const int nS  = SRCT * 8 * 28 * 256;
    const int nW  = NGATE * KA;
    const int nWo = OUTD * HDIM;
    const int nH  = MB * HDIM;
    const int nXd = 8 * 28 * 256;
    const int nB  = 8 * 128;
    const int total = nS + nW + nWo + nH + nXd + nB;
    for (int i = blockIdx.x * blockDim.x + threadIdx.x; i < total; i += gridDim.x * blockDim.x) {
        if (i < nS) {
            int r = i & 255, i2 = i >> 8;
            int m = r >> 3, e = r & 7;
            int oct = i2 % 28, q = i2 / 28;
            int gi = q & 7, t = q >> 3;
            int col = oct * 8 + e, b = gi * 32 + m;
            srcbf[i] = (col < DIN) ? f2bf(src[((size_t)b * SRCT + t) * DIN + col]) : (u16)0;
        } else if (i < nS + nW) {
            int j = i - nS;
            int r = j / KA, col = j % KA;
            u16 v = 0;
            if (col < DIN)       v = f2bf(W_ih[(size_t)r * DIN + col]);
            else if (col >= KXP) v = f2bf(W_hh[(size_t)r * HDIM + (col - KXP)]);
            Wcat[j] = v;
        } else if (i < nS + nW + nWo) {
            int j = i - nS - nW;
            Wo[j] = f2bf(W_out[j]);
        } else if (i < nS + nW + nWo + nH) {
            H[i - nS - nW - nWo] = 0;
        } else if (i < nS + nW + nWo + nH + nXd) {
            Xd[i - nS - nW - nWo - nH] = 0;   // also zeroes the 8 claim counters
        } else {
            bar[i - nS - nW - nWo - nH - nXd] = 0;
        }
    }
}

// ---------------- gate GEMM: direct-load A-fragment pipeline ----------------
// Per-wave tile order (h-first): J<16 -> h-tile, addr hbw + J*512; J>=16 ->
// x-tile xbase_p + (J-16), addr xbw + (J-16)*512; pad tiles (J-16>=xcnt)
// reuse the last x addr with zeroed B. The Xd-ready wait (decoder) is
// injected before issuing the first x load (body J==8), covered by 8
// h-tiles of in-flight loads + 32 MFMAs.
template <int J>
__device__ __forceinline__ void gate_issue2(short8 (&av)[20], const u16* hbw,
                                            const u16* xbw, int xcnt) {
    if constexpr (J < 16) {
        av[J] = ld_l2(hbw + J * 512);
    } else {
        int xt = J - 16; if (xt >= xcnt) xt = xcnt - 1;
        av[J] = ld_l2(xbw + xt * 512);
    }
}
template <int J>
__device__ __forceinline__ void gate_pro2(short8 (&av)[20], const u16* hbw,
                                          const u16* xbw, int xcnt) {
    gate_issue2<J>(av, hbw, xbw, xcnt);
    if constexpr (J + 1 < 8) gate_pro2<J + 1>(av, hbw, xbw, xcnt);
}
template <int J>
__device__ __forceinline__ void gate_body2(short8 (&av)[20], short8 (&Bf)[4][20], f32x16 (&acc)[4],
                                           const u16* hbw, const u16* xbw, int xcnt,
                                           u32* gslots, int pollk) {
    if constexpr (J + 8 < 20) {
        if constexpr (J + 8 == 16) {
            // WG-level Xd-ready wait (uniform: pollk same for all threads).
            // The release syncthreads' vmcnt drain only completes h-loads we
            // need anyway; subsequent vwait<>s become no-ops (values landed).
            if (pollk >= 0) g_wait(gslots, pollk);
        }
        gate_issue2<J + 8>(av, hbw, xbw, xcnt);
    }
    vwait<(J + 8 < 20) ? 8 : (19 - J)>();
    acc[0] = __builtin_amdgcn_mfma_f32_32x32x16_bf16(av[J], Bf[0][J], acc[0], 0, 0, 0);
    acc[1] = __builtin_amdgcn_mfma_f32_32x32x16_bf16(av[J], Bf[1][J], acc[1], 0, 0, 0);
    acc[2] = __builtin_amdgcn_mfma_f32_32x32x16_bf16(av[J], Bf[2][J], acc[2], 0, 0, 0);
    acc[3] = __builtin_amdgcn_mfma_f32_32x32x16_bf16(av[J], Bf[3][J], acc[3], 0, 0, 0);
    if constexpr (J + 1 < 20) gate_body2<J + 1>(av, Bf, acc, hbw, xbw, xcnt, gslots, pollk);
}

// ---------------- out GEMM: direct-load A (h_new), B from Wo ----------------
template <int J>
__device__ __forceinline__ void out_issue(short8 (&av)[16], const u16* hb, int kt0, int lo) {
    const int o2 = 2 * (kt0 + J);
    av[J] = ld_l2(hb + o2 * 256 + lo);
}
template <int J>
__device__ __forceinline__ void out_pro(short8 (&av)[16], const u16* hb, int kt0, int lo) {
    out_issue<J>(av, hb, kt0, lo);
    if constexpr (J + 1 < 8) out_pro<J + 1>(av, hb, kt0, lo);
}
template <int J>
__device__ __forceinline__ void out_body(short8 (&av)[16], f32x16& oacc, const u16* hb,
                                         const u16* wob, int kt0, int lo) {
    if constexpr (J + 8 < 16) out_issue<J + 8>(av, hb, kt0, lo);
    vwait<(J + 8 < 16) ? 8 : (15 - J)>();
    short8 bf = *(const short8*)(wob + (size_t)(kt0 + J) * 16);
    oacc = __builtin_amdgcn_mfma_f32_32x32x16_bf16(av[J], bf, oacc, 0, 0, 0);
    if constexpr (J + 1 < 16) out_body<J + 1>(av, oacc, hb, wob, kt0, lo);
}

// ---------------- persistent LSTM ----------------
// group g = XCD id (HW_REG_XCC_ID), slice s = per-XCD claim (0..31).
// All group DATA traffic intra-XCD (local L2, plain stores + sc0 loads);
// barrier FLAGS on the AGENT/IC path, 4-way striped arrivals, tid0 polls.
__global__ void __launch_bounds__(256, 1)
lstm_persist(const u16* __restrict__ srcbf, u16* __restrict__ H,
             u16* __restrict__ Xd, const u16* __restrict__ Wcat,
             const u16* __restrict__ Wo,
             const float* __restrict__ b_ih, const float* __restrict__ b_hh,
             const float* __restrict__ b_out,
             float* __restrict__ dout, u32* __restrict__ bar)
{
    __shared__ __align__(16) float G2[16 * 32 * 36];   // [slab][col][b36] 73,728 B
    __shared__ __align__(16) u16  Hx[4 * 32 * 8];      // transpose tile 2 KB
    __shared__ __align__(16) char lds_pad[8192];       // >80KB => 1 WG/CU (claim needs it)
    __shared__ int gs_share[2];

    const int tid  = threadIdx.x;
    const int p    = tid >> 6;
    const int lane = tid & 63;
    const int l31  = lane & 31;
    const int kg   = lane >> 5;
    const int lo   = kg * 256 + l31 * 8;

    if (tid == 255) *(volatile char*)lds_pad = 0;      // keep pad allocated

    // ---- XCD discovery + slice claim (counters in Xd[0..7], zeroed by prep) ----
    if (tid == 0) {
        u32 xcc;
        asm volatile("s_getreg_b32 %0, hwreg(HW_REG_XCC_ID)" : "=s"(xcc));
        u32 myidx = __hip_atomic_fetch_add((u32*)Xd + xcc, 1u,
                                           __ATOMIC_RELAXED, __HIP_MEMORY_SCOPE_AGENT);
        gs_share[0] = (int)xcc;
        gs_share[1] = (int)myidx;
    }
    __syncthreads();
    const int g  = gs_share[0];
    const int s  = gs_share[1];
    const int b0 = g * 32;

    u32* gslots = bar + g * 128;
    u16* Xdg = Xd + (size_t)g * 7168;

    // K-split (h-first order): wave p owns h-tiles kt=14+p*16+{0..15} and
    // x-tiles kt=xbase_p+{0..xcnt_p-1}; xcnt={4,4,3,3}, xbase={0,4,8,11}.
    const int xcnt  = (p < 2) ? 4 : 3;
    const int xbase = p * 4 - (p == 3 ? 1 : 0);

    // ---- pin B for all 4 gates in the per-wave tile order (pads zeroed) ----
    short8 Bfrag[4][20];
#pragma unroll
    for (int gg = 0; gg < 4; ++gg) {
        const u16* pw = Wcat + (size_t)(gg * 1024 + s * 32 + l31) * KA + kg * 8;
#pragma unroll
        for (int j = 0; j < 20; ++j) {
            int kt; bool valid = true;
            if (j < 16) kt = 14 + p * 16 + j;
            else { int xt = j - 16; if (xt < xcnt) kt = xbase + xt; else { kt = 0; valid = false; } }
            Bfrag[gg][j] = valid ? *(const short8*)(pw + (size_t)kt * 16) : short8{};
        }
    }

    // pointwise mapping: thread -> (col cs, 4 batches bq*4..)
    const int cs = tid & 31;
    const int bq = tid >> 5;
    float creg[4] = {0.f, 0.f, 0.f, 0.f};
    const int hcg = s * 32 + cs;
    const float bI  = b_ih[hcg]        + b_hh[hcg];
    const float bF  = b_ih[1024 + hcg] + b_hh[1024 + hcg];
    const float bG_ = b_ih[2048 + hcg] + b_hh[2048 + hcg];
    const float bO  = b_ih[3072 + hcg] + b_hh[3072 + hcg];
    const float bOutv = (s < 7 && hcg < OUTD) ? b_out[hcg] : 0.f;

    for (int t = 0; t < NSTEP; ++t) {
        const u16* hb    = H + (size_t)(t & 1) * (MB * HDIM) + (size_t)g * 32768;  // h_t
        u16*       HTn   = H + (size_t)((t + 1) & 1) * (MB * HDIM);
        const u16* hnext = HTn + (size_t)g * 32768;                                // h_{t+1}
        const u16* xb;
        if (t < SRCT)       xb = srcbf + (size_t)(t * 8 + g) * 7168;
        else if (t == SRCT) xb = srcbf + (size_t)((SRCT - 1) * 8 + g) * 7168;
        else                xb = Xdg;

        // deferred waits: s>=7 decoder WGs certify h here (they skipped the k1
        // wait); everyone certifies Xd inside the pipeline at J==8.
        const int upk   = (t > SRCT && s >= 7) ? (2 * t - SRCT - 2) : -1;  // h-ready
        const int pollk = (t > SRCT)           ? (2 * t - SRCT - 1) : -1;  // Xd-ready
        if (upk >= 0) g_wait(gslots, upk);

        // ---- gate GEMM: pipelined L2 loads feeding pinned-B MFMAs ----
        f32x16 acc[4] = {f32x16{}, f32x16{}, f32x16{}, f32x16{}};
        {
            short8 av[20];
            const u16* hbw = hb + p * 8192 + lo;
            const u16* xbw = xb + (size_t)xbase * 512 + lo;
            gate_pro2<0>(av, hbw, xbw, xcnt);
            gate_body2<0>(av, Bfrag, acc, hbw, xbw, xcnt, gslots, pollk);
        }
#pragma unroll
        for (int gg = 0; gg < 4; ++gg) {
#pragma unroll
            for (int rq = 0; rq < 4; ++rq) {
                f32x4 v;
                v[0] = acc[gg][rq * 4 + 0]; v[1] = acc[gg][rq * 4 + 1];
                v[2] = acc[gg][rq * 4 + 2]; v[3] = acc[gg][rq * 4 + 3];
                *(f32x4*)&G2[(size_t)((gg * 4 + p) * 32 + l31) * 36 + rq * 8 + kg * 4] = v;
            }
        }
        __syncthreads();

        // ---- pointwise cell ----
        {
            f32x4 sg[4];
#pragma unroll
            for (int gg = 0; gg < 4; ++gg) {
                f32x4 a = *(const f32x4*)&G2[(size_t)((gg * 4 + 0) * 32 + cs) * 36 + bq * 4];
#pragma unroll
                for (int pp = 1; pp < 4; ++pp)
                    a += *(const f32x4*)&G2[(size_t)((gg * 4 + pp) * 32 + cs) * 36 + bq * 4];
                sg[gg] = a;
            }
#pragma unroll
            for (int i = 0; i < 4; ++i) {
                float gi = sg[0][i] + bI, gf = sg[1][i] + bF;
                float gG = sg[2][i] + bG_, go = sg[3][i] + bO;
                float c = sigm(gf) * creg[i] + sigm(gi) * tanh_(gG);
                creg[i] = c;
                Hx[(cs >> 3) * 256 + (bq * 4 + i) * 8 + (cs & 7)] = f2bf(sigm(go) * tanh_(c));
            }
        }
        __syncthreads();
        // coalesced write-through of this WG's h slice into the LOCAL L2
        pstore((u64*)HTn + (size_t)g * 8192 + s * 256 + tid, ((const u64*)Hx)[tid]);

        if (t < SRCT) {
            g_arrive(gslots, t, s);
            g_wait(gslots, t);              // h_{t+1} ready; next gate runs free
        } else {
            const int d  = t - SRCT;
            const int k1 = SRCT + 2 * d;
            g_arrive(gslots, k1, s);
            if (s < 7) {
                g_wait(gslots, k1);         // h_{t+1} ready for out-GEMM
                f32x16 oacc = {};
                const int orow = (s * 32 + l31 < OUTD) ? (s * 32 + l31) : (OUTD - 1);
                const u16* wob = Wo + (size_t)orow * HDIM + kg * 8;
                short8 av2[16];
                out_pro<0>(av2, hnext, p * 16, lo);
                out_body<0>(av2, oacc, hnext, wob, p * 16, lo);
#pragma unroll
                for (int rq = 0; rq < 4; ++rq) {
                    f32x4 v;
                    v[0] = oacc[rq * 4 + 0]; v[1] = oacc[rq * 4 + 1];
                    v[2] = oacc[rq * 4 + 2]; v[3] = oacc[rq * 4 + 3];
                    *(f32x4*)&G2[(size_t)(p * 32 + l31) * 36 + rq * 8 + kg * 4] = v;
                }
                __syncthreads();
                {
                    const int  ocol = s * 32 + cs;
                    const bool real = ocol < OUTD;
                    f32x4 S = *(const f32x4*)&G2[(size_t)(0 * 32 + cs) * 36 + bq * 4];
#pragma unroll
                    for (int pp = 1; pp < 4; ++pp)
                        S += *(const f32x4*)&G2[(size_t)(pp * 32 + cs) * 36 + bq * 4];
#pragma unroll
                    for (int i = 0; i < 4; ++i) {
                        float v = real ? (S[i] + bOutv) : 0.f;
                        Hx[(cs >> 3) * 256 + (bq * 4 + i) * 8 + (cs & 7)] = real ? f2bf(v) : (u16)0;
                        if (real)
                            dout[(size_t)(b0 + bq * 4 + i) * (DECT * OUTD) + (size_t)d * OUTD + ocol] = v;
                    }
                }
                __syncthreads();
                pstore((u64*)Xdg + s * 256 + tid, ((const u64*)Hx)[tid]);
                if (t < NSTEP - 1)
                    g_arrive(gslots, k1 + 1, s);   // Xd ready (syncthreads drains stores)
            } else {
                // nothing produced since k1: arrive at k1+1 immediately; the
                // h-ready (k1) wait is deferred to next gate's upfront poll.
                if (t < NSTEP - 1 && tid == 0)
                    flag_add(gslots, k1 + 1, s);
            }
        }
    }
}

extern "C" void kernel_launch(void* const* d_in, const int* in_sizes, int n_in,
                              void* d_out, int out_size, void* d_ws, size_t ws_size,
                              hipStream_t stream) {
    const float* src   = (const float*)d_in[0];
    // d_in[1] = tgt (unused in eval forward)
    const float* W_ih  = (const float*)d_in[2];
    const float* W_hh  = (const float*)d_in[3];
    const float* b_ih  = (const float*)d_in[4];
    const float* b_hh  = (const float*)d_in[5];
    const float* W_out = (const float*)d_in[6];
    const float* b_out = (const float*)d_in[7];
    float* out = (float*)d_out;

    char* ws = (char*)d_ws;
    u16* srcbf = (u16*)(ws + OFF_SRCBF);
    u16* H     = (u16*)(ws + OFF_H);
    u16* Xd    = (u16*)(ws + OFF_XDEC);
    u16* Wcat  = (u16*)(ws + OFF_WCAT);
    u16* Wo    = (u16*)(ws + OFF_WO);
    u32* bar   = (u32*)(ws + OFF_BAR);

    hipLaunchKernelGGL(prep_kernel, dim3(2048), dim3(256), 0, stream,
                       src, W_ih, W_hh, W_out, srcbf, H, Xd, Wcat, Wo, bar);

    hipLaunchKernelGGL(lstm_persist, dim3(NWG), dim3(256), 0, stream,
                       srcbf, H, Xd, Wcat, Wo, b_ih, b_hh, b_out, out, bar);
}

// Round 7
// 770.137 us; speedup vs baseline: 1.5529x; 1.2629x over previous
//
#include <hip/hip_runtime.h>
#include <hip/hip_bf16.h>

typedef unsigned short u16;
typedef unsigned int   u32;
typedef unsigned long long u64;
typedef __attribute__((ext_vector_type(4)))  float  f32x4;
typedef __attribute__((ext_vector_type(8)))  short  short8;
typedef __attribute__((ext_vector_type(16))) float  f32x16;

#define MB     256
#define SRCT   120
#define DECT   24
#define NSTEP  144
#define DIN    216
#define HDIM   1024
#define KXP    224
#define KA     1248
#define NGATE  4096
#define OUTD   216
#define NWG    256

// ---- ws layout (bytes) ----
#define OFF_SRCBF 0u
#define OFF_H     13762560u
#define OFF_XDEC  14811136u
#define OFF_WCAT  14925824u
#define OFF_WO    25149440u
#define OFF_BAR   25591808u      // 8 groups x 128 u32 (slots 0..63 used, accumulating)

__device__ __forceinline__ u16 f2bf(float f) {
    union { float f; unsigned v; } c; c.f = f;
    return (u16)((c.v + 0x7FFFu + ((c.v >> 16) & 1u)) >> 16);
}
__device__ __forceinline__ float sigm(float x)  { return 1.0f / (1.0f + __expf(-x)); }
__device__ __forceinline__ float tanh_(float x) { return 1.0f - 2.0f / (1.0f + __expf(2.0f * x)); }

// plain write-back store: lands in the LOCAL XCD L2 (group == XCD).
__device__ __forceinline__ void pstore(u64* p, u64 v) { *p = v; }

// L2-coherent 16B load: sc0 bypasses L1, hits the XCD-local L2. [proven R2]
__device__ __forceinline__ short8 ld_l2(const u16* p) {
    short8 r;
    asm volatile("global_load_dwordx4 %0, %1, off sc0" : "=v"(r) : "v"(p));
    return r;
}
template <int N>
__device__ __forceinline__ void vwait() {
    asm volatile("s_waitcnt vmcnt(%0)" :: "n"(N));
    __builtin_amdgcn_sched_barrier(0);   // keep MFMAs from hoisting above the wait
}

// ---- group barrier: R2-proven IC-atomic flags, single slot, backoff poll ----
// EMPIRICAL RULE (R2/R4/R5 pass, R3/R6 fail): spin flags must be AGENT-scope
// atomics end-to-end; L2-local flag schemes (bare atomic or plain store +
// sc0 poll) hang. Cost model (R2 vs R4 vs R5): barrier cost ∝ poll traffic
// at the IC line. So: ONE slot per barrier (k&63, accumulating, target
// 32*((k>>6)+1)); tid0-only pollers; two-phase backoff to cut poll rate
// ~10x in the tail (6 quick checks @ s_sleep(2), then s_sleep(16) cap).
__device__ __forceinline__ void flag_add(u32* gslots, int k) {
    __hip_atomic_fetch_add(gslots + (k & 63), 1u,
                           __ATOMIC_RELAXED, __HIP_MEMORY_SCOPE_AGENT);
}
__device__ __forceinline__ void g_arrive(u32* gslots, int k) {
    __syncthreads();   // each wave drains vmcnt(0) before s_barrier => stores in L2
    if (threadIdx.x == 0) {
        asm volatile("s_waitcnt vmcnt(0)" ::: "memory");
        flag_add(gslots, k);
    }
}
__device__ __forceinline__ void g_wait(u32* gslots, int k) {
    if (threadIdx.x == 0) {
        const u32 tgt = 32u * (u32)((k >> 6) + 1);
        const u32* a = gslots + (k & 63);
        int tries = 0;
        while (__hip_atomic_load(a, __ATOMIC_RELAXED, __HIP_MEMORY_SCOPE_AGENT) < tgt) {
            if (++tries < 6) __builtin_amdgcn_s_sleep(2);
            else             __builtin_amdgcn_s_sleep(16);
        }
    }
    __syncthreads();
}

// ---------------- prep: fp32 -> bf16, transposed comm layouts ----------------
__global__ void prep_kernel(const float* __restrict__ src,
                            const float* __restrict__ W_ih,
                            const float* __restrict__ W_hh,
                            const float* __restrict__ W_out,
                            u16* __restrict__ srcbf, u16* __restrict__ H,
                            u16* __restrict__ Xd,    u16* __restrict__ Wcat,
                            u16* __restrict__ Wo,    u32* __restrict__ bar) {
    const int nS  = SRCT * 8 * 28 * 256;
    const int nW  = NGATE * KA;
    const int nWo = OUTD * HDIM;
    const int nH  = MB * HDIM;
    const int nXd = 8 * 28 * 256;
    const int nB  = 8 * 128;
    const int total = nS + nW + nWo + nH + nXd + nB;
    for (int i = blockIdx.x * blockDim.x + threadIdx.x; i < total; i += gridDim.x * blockDim.x) {
        if (i < nS) {
            int r = i & 255, i2 = i >> 8;
            int m = r >> 3, e = r & 7;
            int oct = i2 % 28, q = i2 / 28;
            int gi = q & 7, t = q >> 3;
            int col = oct * 8 + e, b = gi * 32 + m;
            srcbf[i] = (col < DIN) ? f2bf(src[((size_t)b * SRCT + t) * DIN + col]) : (u16)0;
        } else if (i < nS + nW) {
            int j = i - nS;
            int r = j / KA, col = j % KA;
            u16 v = 0;
            if (col < DIN)       v = f2bf(W_ih[(size_t)r * DIN + col]);
            else if (col >= KXP) v = f2bf(W_hh[(size_t)r * HDIM + (col - KXP)]);
            Wcat[j] = v;
        } else if (i < nS + nW + nWo) {
            int j = i - nS - nW;
            Wo[j] = f2bf(W_out[j]);
        } else if (i < nS + nW + nWo + nH) {
            H[i - nS - nW - nWo] = 0;
        } else if (i < nS + nW + nWo + nH + nXd) {
            Xd[i - nS - nW - nWo - nH] = 0;   // also zeroes the 8 claim counters
        } else {
            bar[i - nS - nW - nWo - nH - nXd] = 0;
        }
    }
}

// ---------------- gate GEMM: direct-load A-fragment pipeline ----------------
// Per-wave tile order (h-first): J<16 -> h-tile, addr hbw + J*512; J>=16 ->
// x-tile xbase_p + (J-16), addr xbw + (J-16)*512; pad tiles (J-16>=xcnt)
// reuse the last x addr with zeroed B. The Xd-ready wait (decoder) is
// injected before issuing the first x load (body J==8), covered by 8
// h-tiles of in-flight loads + 32 MFMAs.
template <int J>
__device__ __forceinline__ void gate_issue2(short8 (&av)[20], const u16* hbw,
                                            const u16* xbw, int xcnt) {
    if constexpr (J < 16) {
        av[J] = ld_l2(hbw + J * 512);
    } else {
        int xt = J - 16; if (xt >= xcnt) xt = xcnt - 1;
        av[J] = ld_l2(xbw + xt * 512);
    }
}
template <int J>
__device__ __forceinline__ void gate_pro2(short8 (&av)[20], const u16* hbw,
                                          const u16* xbw, int xcnt) {
    gate_issue2<J>(av, hbw, xbw, xcnt);
    if constexpr (J + 1 < 8) gate_pro2<J + 1>(av, hbw, xbw, xcnt);
}
template <int J>
__device__ __forceinline__ void gate_body2(short8 (&av)[20], short8 (&Bf)[4][20], f32x16 (&acc)[4],
                                           const u16* hbw, const u16* xbw, int xcnt,
                                           u32* gslots, int pollk) {
    if constexpr (J + 8 < 20) {
        if constexpr (J + 8 == 16) {
            // WG-level Xd-ready wait (uniform pollk across the WG).
            if (pollk >= 0) g_wait(gslots, pollk);
        }
        gate_issue2<J + 8>(av, hbw, xbw, xcnt);
    }
    vwait<(J + 8 < 20) ? 8 : (19 - J)>();
    acc[0] = __builtin_amdgcn_mfma_f32_32x32x16_bf16(av[J], Bf[0][J], acc[0], 0, 0, 0);
    acc[1] = __builtin_amdgcn_mfma_f32_32x32x16_bf16(av[J], Bf[1][J], acc[1], 0, 0, 0);
    acc[2] = __builtin_amdgcn_mfma_f32_32x32x16_bf16(av[J], Bf[2][J], acc[2], 0, 0, 0);
    acc[3] = __builtin_amdgcn_mfma_f32_32x32x16_bf16(av[J], Bf[3][J], acc[3], 0, 0, 0);
    if constexpr (J + 1 < 20) gate_body2<J + 1>(av, Bf, acc, hbw, xbw, xcnt, gslots, pollk);
}

// ---------------- out GEMM: direct-load A (h_new), B from Wo ----------------
template <int J>
__device__ __forceinline__ void out_issue(short8 (&av)[16], const u16* hb, int kt0, int lo) {
    const int o2 = 2 * (kt0 + J);
    av[J] = ld_l2(hb + o2 * 256 + lo);
}
template <int J>
__device__ __forceinline__ void out_pro(short8 (&av)[16], const u16* hb, int kt0, int lo) {
    out_issue<J>(av, hb, kt0, lo);
    if constexpr (J + 1 < 8) out_pro<J + 1>(av, hb, kt0, lo);
}
template <int J>
__device__ __forceinline__ void out_body(short8 (&av)[16], f32x16& oacc, const u16* hb,
                                         const u16* wob, int kt0, int lo) {
    if constexpr (J + 8 < 16) out_issue<J + 8>(av, hb, kt0, lo);
    vwait<(J + 8 < 16) ? 8 : (15 - J)>();
    short8 bf = *(const short8*)(wob + (size_t)(kt0 + J) * 16);
    oacc = __builtin_amdgcn_mfma_f32_32x32x16_bf16(av[J], bf, oacc, 0, 0, 0);
    if constexpr (J + 1 < 16) out_body<J + 1>(av, oacc, hb, wob, kt0, lo);
}

// ---------------- persistent LSTM ----------------
// group g = XCD id (HW_REG_XCC_ID), slice s = per-XCD claim (0..31).
// All group DATA traffic intra-XCD (local L2, plain stores + sc0 loads);
// barrier FLAGS on the AGENT/IC atomic path (empirically mandatory).
__global__ void __launch_bounds__(256, 1)
lstm_persist(const u16* __restrict__ srcbf, u16* __restrict__ H,
             u16* __restrict__ Xd, const u16* __restrict__ Wcat,
             const u16* __restrict__ Wo,
             const float* __restrict__ b_ih, const float* __restrict__ b_hh,
             const float* __restrict__ b_out,
             float* __restrict__ dout, u32* __restrict__ bar)
{
    __shared__ __align__(16) float G2[16 * 32 * 36];   // [slab][col][b36] 73,728 B
    __shared__ __align__(16) u16  Hx[4 * 32 * 8];      // transpose tile 2 KB
    __shared__ __align__(16) char lds_pad[8192];       // >80KB => 1 WG/CU (claim needs it)
    __shared__ int gs_share[2];

    const int tid  = threadIdx.x;
    const int p    = tid >> 6;
    const int lane = tid & 63;
    const int l31  = lane & 31;
    const int kg   = lane >> 5;
    const int lo   = kg * 256 + l31 * 8;

    if (tid == 255) *(volatile char*)lds_pad = 0;      // keep pad allocated

    // ---- XCD discovery + slice claim (counters in Xd[0..7], zeroed by prep) ----
    if (tid == 0) {
        u32 xcc;
        asm volatile("s_getreg_b32 %0, hwreg(HW_REG_XCC_ID)" : "=s"(xcc));
        u32 myidx = __hip_atomic_fetch_add((u32*)Xd + xcc, 1u,
                                           __ATOMIC_RELAXED, __HIP_MEMORY_SCOPE_AGENT);
        gs_share[0] = (int)xcc;
        gs_share[1] = (int)myidx;
    }
    __syncthreads();
    const int g  = gs_share[0];
    const int s  = gs_share[1];
    const int b0 = g * 32;

    u32* gslots = bar + g * 128;
    u16* Xdg = Xd + (size_t)g * 7168;

    // K-split (h-first order): wave p owns h-tiles kt=14+p*16+{0..15} and
    // x-tiles kt=xbase_p+{0..xcnt_p-1}; xcnt={4,4,3,3}, xbase={0,4,8,11}.
    const int xcnt  = (p < 2) ? 4 : 3;
    const int xbase = p * 4 - (p == 3 ? 1 : 0);

    // ---- pin B for all 4 gates in the per-wave tile order (pads zeroed) ----
    short8 Bfrag[4][20];
#pragma unroll
    for (int gg = 0; gg < 4; ++gg) {
        const u16* pw = Wcat + (size_t)(gg * 1024 + s * 32 + l31) * KA + kg * 8;
#pragma unroll
        for (int j = 0; j < 20; ++j) {
            int kt; bool valid = true;
            if (j < 16) kt = 14 + p * 16 + j;
            else { int xt = j - 16; if (xt < xcnt) kt = xbase + xt; else { kt = 0; valid = false; } }
            Bfrag[gg][j] = valid ? *(const short8*)(pw + (size_t)kt * 16) : short8{};
        }
    }

    // pointwise mapping: thread -> (col cs, 4 batches bq*4..)
    const int cs = tid & 31;
    const int bq = tid >> 5;
    float creg[4] = {0.f, 0.f, 0.f, 0.f};
    const int hcg = s * 32 + cs;
    const float bI  = b_ih[hcg]        + b_hh[hcg];
    const float bF  = b_ih[1024 + hcg] + b_hh[1024 + hcg];
    const float bG_ = b_ih[2048 + hcg] + b_hh[2048 + hcg];
    const float bO  = b_ih[3072 + hcg] + b_hh[3072 + hcg];
    const float bOutv = (s < 7 && hcg < OUTD) ? b_out[hcg] : 0.f;

    for (int t = 0; t < NSTEP; ++t) {
        const u16* hb    = H + (size_t)(t & 1) * (MB * HDIM) + (size_t)g * 32768;  // h_t
        u16*       HTn   = H + (size_t)((t + 1) & 1) * (MB * HDIM);
        const u16* hnext = HTn + (size_t)g * 32768;                                // h_{t+1}
        const u16* xb;
        if (t < SRCT)       xb = srcbf + (size_t)(t * 8 + g) * 7168;
        else if (t == SRCT) xb = srcbf + (size_t)((SRCT - 1) * 8 + g) * 7168;
        else                xb = Xdg;

        // deferred waits: s>=7 decoder WGs certify h here (they skipped the k1
        // wait); everyone certifies Xd inside the pipeline at J==8.
        const int upk   = (t > SRCT && s >= 7) ? (2 * t - SRCT - 2) : -1;  // h-ready
        const int pollk = (t > SRCT)           ? (2 * t - SRCT - 1) : -1;  // Xd-ready
        if (upk >= 0) g_wait(gslots, upk);

        // ---- gate GEMM: pipelined L2 loads feeding pinned-B MFMAs ----
        f32x16 acc[4] = {f32x16{}, f32x16{}, f32x16{}, f32x16{}};
        {
            short8 av[20];
            const u16* hbw = hb + p * 8192 + lo;
            const u16* xbw = xb + (size_t)xbase * 512 + lo;
            gate_pro2<0>(av, hbw, xbw, xcnt);
            gate_body2<0>(av, Bfrag, acc, hbw, xbw, xcnt, gslots, pollk);
        }
#pragma unroll
        for (int gg = 0; gg < 4; ++gg) {
#pragma unroll
            for (int rq = 0; rq < 4; ++rq) {
                f32x4 v;
                v[0] = acc[gg][rq * 4 + 0]; v[1] = acc[gg][rq * 4 + 1];
                v[2] = acc[gg][rq * 4 + 2]; v[3] = acc[gg][rq * 4 + 3];
                *(f32x4*)&G2[(size_t)((gg * 4 + p) * 32 + l31) * 36 + rq * 8 + kg * 4] = v;
            }
        }
        __syncthreads();

        // ---- pointwise cell ----
        {
            f32x4 sg[4];
#pragma unroll
            for (int gg = 0; gg < 4; ++gg) {
                f32x4 a = *(const f32x4*)&G2[(size_t)((gg * 4 + 0) * 32 + cs) * 36 + bq * 4];
#pragma unroll
                for (int pp = 1; pp < 4; ++pp)
                    a += *(const f32x4*)&G2[(size_t)((gg * 4 + pp) * 32 + cs) * 36 + bq * 4];
                sg[gg] = a;
            }
#pragma unroll
            for (int i = 0; i < 4; ++i) {
                float gi = sg[0][i] + bI, gf = sg[1][i] + bF;
                float gG = sg[2][i] + bG_, go = sg[3][i] + bO;
                float c = sigm(gf) * creg[i] + sigm(gi) * tanh_(gG);
                creg[i] = c;
                Hx[(cs >> 3) * 256 + (bq * 4 + i) * 8 + (cs & 7)] = f2bf(sigm(go) * tanh_(c));
            }
        }
        __syncthreads();
        // coalesced write-through of this WG's h slice into the LOCAL L2
        pstore((u64*)HTn + (size_t)g * 8192 + s * 256 + tid, ((const u64*)Hx)[tid]);

        if (t < SRCT) {
            g_arrive(gslots, t);
            g_wait(gslots, t);              // h_{t+1} ready; next gate runs free
        } else {
            const int d  = t - SRCT;
            const int k1 = SRCT + 2 * d;
            g_arrive(gslots, k1);
            if (s < 7) {
                g_wait(gslots, k1);         // h_{t+1} ready for out-GEMM
                f32x16 oacc = {};
                const int orow = (s * 32 + l31 < OUTD) ? (s * 32 + l31) : (OUTD - 1);
                const u16* wob = Wo + (size_t)orow * HDIM + kg * 8;
                short8 av2[16];
                out_pro<0>(av2, hnext, p * 16, lo);
                out_body<0>(av2, oacc, hnext, wob, p * 16, lo);
#pragma unroll
                for (int rq = 0; rq < 4; ++rq) {
                    f32x4 v;
                    v[0] = oacc[rq * 4 + 0]; v[1] = oacc[rq * 4 + 1];
                    v[2] = oacc[rq * 4 + 2]; v[3] = oacc[rq * 4 + 3];
                    *(f32x4*)&G2[(size_t)(p * 32 + l31) * 36 + rq * 8 + kg * 4] = v;
                }
                __syncthreads();
                {
                    const int  ocol = s * 32 + cs;
                    const bool real = ocol < OUTD;
                    f32x4 S = *(const f32x4*)&G2[(size_t)(0 * 32 + cs) * 36 + bq * 4];
#pragma unroll
                    for (int pp = 1; pp < 4; ++pp)
                        S += *(const f32x4*)&G2[(size_t)(pp * 32 + cs) * 36 + bq * 4];
#pragma unroll
                    for (int i = 0; i < 4; ++i) {
                        float v = real ? (S[i] + bOutv) : 0.f;
                        Hx[(cs >> 3) * 256 + (bq * 4 + i) * 8 + (cs & 7)] = real ? f2bf(v) : (u16)0;
                        if (real)
                            dout[(size_t)(b0 + bq * 4 + i) * (DECT * OUTD) + (size_t)d * OUTD + ocol] = v;
                    }
                }
                __syncthreads();
                pstore((u64*)Xdg + s * 256 + tid, ((const u64*)Hx)[tid]);
                if (t < NSTEP - 1)
                    g_arrive(gslots, k1 + 1);   // Xd ready (syncthreads drains stores)
            } else {
                // nothing produced since k1: arrive at k1+1 immediately; the
                // h-ready (k1) wait is deferred to next gate's upfront poll.
                if (t < NSTEP - 1 && tid == 0)
                    flag_add(gslots, k1 + 1);
            }
        }
    }
}

extern "C" void kernel_launch(void* const* d_in, const int* in_sizes, int n_in,
                              void* d_out, int out_size, void* d_ws, size_t ws_size,
                              hipStream_t stream) {
    const float* src   = (const float*)d_in[0];
    // d_in[1] = tgt (unused in eval forward)
    const float* W_ih  = (const float*)d_in[2];
    const float* W_hh  = (const float*)d_in[3];
    const float* b_ih  = (const float*)d_in[4];
    const float* b_hh  = (const float*)d_in[5];
    const float* W_out = (const float*)d_in[6];
    const float* b_out = (const float*)d_in[7];
    float* out = (float*)d_out;

    char* ws = (char*)d_ws;
    u16* srcbf = (u16*)(ws + OFF_SRCBF);
    u16* H     = (u16*)(ws + OFF_H);
    u16* Xd    = (u16*)(ws + OFF_XDEC);
    u16* Wcat  = (u16*)(ws + OFF_WCAT);
    u16* Wo    = (u16*)(ws + OFF_WO);
    u32* bar   = (u32*)(ws + OFF_BAR);

    hipLaunchKernelGGL(prep_kernel, dim3(2048), dim3(256), 0, stream,
                       src, W_ih, W_hh, W_out, srcbf, H, Xd, Wcat, Wo, bar);

    hipLaunchKernelGGL(lstm_persist, dim3(NWG), dim3(256), 0, stream,
                       srcbf, H, Xd, Wcat, Wo, b_ih, b_hh, b_out, out, bar);
}